// Round 5
// baseline (306.151 us; speedup 1.0000x reference)
//
#include <hip/hip_runtime.h>
#include <hip/hip_bf16.h>

// ---------------------------------------------------------------------------
// VGAE forward, round 5: same as round 4, but the graph-captured
// hipMemsetAsync (measured ~115us as a rocclr fill node) is replaced by a
// plain zeroing kernel (~5us).
//
// d_ws layout:
//   isq_out [n], isq_in [n]
//   bufA [64n]  : h_pre (gemm1 out) -> t23 (gemm23 out)
//   bufB [64n]  : h (gather1 out, gemm23 in)
//   wc   [64*64]: [W2|W3] combined f32, natural [k][col]
//   w1f  [32768 shorts]: W1 as bf16, MFMA-fragment-linear
//   ints: row_ptr[n+1], cursor[n], partials[512], edge_src[e]
//   (degS/degD ints overlay bufA before gemm1 runs)
// ---------------------------------------------------------------------------

typedef __attribute__((ext_vector_type(8))) short short8;
typedef __attribute__((ext_vector_type(4))) float f32x4;

static __device__ inline short f2bf(float f)
{
    union { __hip_bfloat16 h; short s; } u;
    u.h = __float2bfloat16(f);
    return u.s;
}

static __device__ inline short8 cvt8(float4 lo, float4 hi)
{
    short8 r;
    r[0] = f2bf(lo.x); r[1] = f2bf(lo.y); r[2] = f2bf(lo.z); r[3] = f2bf(lo.w);
    r[4] = f2bf(hi.x); r[5] = f2bf(hi.y); r[6] = f2bf(hi.z); r[7] = f2bf(hi.w);
    return r;
}

__global__ __launch_bounds__(256) void k_zero(int4* __restrict__ p, int total4)
{
    int gid = blockIdx.x * 256 + threadIdx.x;
    if (gid < total4) p[gid] = make_int4(0, 0, 0, 0);
}

// ---- setup: W1 [512][64] f32 -> fragment-linear bf16 ----
__global__ __launch_bounds__(256) void k_pack_w1(
    const float* __restrict__ W1, short* __restrict__ w1f)
{
    int gid = blockIdx.x * 256 + threadIdx.x;
    if (gid >= 512 * 64) return;
    int k = gid >> 6, c = gid & 63;
    int kt = k >> 5, kk = k & 31, nt = c >> 4, lr = c & 15;
    int kg = kk >> 3, j = kk & 7;
    int l = kg * 16 + lr;
    w1f[(kt * 4 + nt) * 512 + l * 8 + j] = f2bf(W1[gid]);
}

__global__ __launch_bounds__(256) void k_build_wc(
    const float* __restrict__ W2, const float* __restrict__ W3,
    float* __restrict__ wc)
{
    int gid = blockIdx.x * 256 + threadIdx.x;
    if (gid >= 64 * 64) return;
    int k = gid >> 6, c = gid & 63;
    wc[gid] = (c < 32) ? W2[k * 32 + c] : W3[k * 32 + (c - 32)];
}

__global__ __launch_bounds__(256) void k_deg_int(
    const int* __restrict__ src, const int* __restrict__ dst,
    int* __restrict__ degS, int* __restrict__ degD, int e)
{
    int gid = blockIdx.x * 256 + threadIdx.x;
    if (gid >= e) return;
    atomicAdd(&degS[src[gid]], 1);
    atomicAdd(&degD[dst[gid]], 1);
}

__global__ __launch_bounds__(256) void k_scan_block_sums(
    const int* __restrict__ deg, int* __restrict__ partials, int n)
{
    __shared__ int red[256];
    int gid = blockIdx.x * 256 + threadIdx.x;
    red[threadIdx.x] = (gid < n) ? deg[gid] : 0;
    __syncthreads();
    for (int s = 128; s > 0; s >>= 1) {
        if (threadIdx.x < s) red[threadIdx.x] += red[threadIdx.x + s];
        __syncthreads();
    }
    if (threadIdx.x == 0) partials[blockIdx.x] = red[0];
}

__global__ __launch_bounds__(512) void k_scan_partials(
    int* __restrict__ partials, int nb)
{
    __shared__ int s[512];
    int t = threadIdx.x;
    s[t] = (t < nb) ? partials[t] : 0;
    __syncthreads();
    for (int d = 1; d < 512; d <<= 1) {
        int v = (t >= d) ? s[t - d] : 0;
        __syncthreads();
        s[t] += v;
        __syncthreads();
    }
    if (t < nb) partials[t] = (t == 0) ? 0 : s[t - 1];
}

__global__ __launch_bounds__(256) void k_scan_final(
    const int* __restrict__ degD, const int* __restrict__ degS,
    const int* __restrict__ partials,
    int* __restrict__ row_ptr, int* __restrict__ cursor,
    float* __restrict__ isq_out, float* __restrict__ isq_in, int n)
{
    __shared__ int s[256];
    int t = threadIdx.x;
    int gid = blockIdx.x * 256 + t;
    int v = (gid < n) ? degD[gid] : 0;
    s[t] = v;
    __syncthreads();
    for (int d = 1; d < 256; d <<= 1) {
        int u = (t >= d) ? s[t - d] : 0;
        __syncthreads();
        s[t] += u;
        __syncthreads();
    }
    int start = partials[blockIdx.x] + s[t] - v;
    if (gid < n) {
        row_ptr[gid] = start;
        cursor[gid]  = start;
        isq_in[gid]  = 1.0f / sqrtf((float)max(v, 1));
        isq_out[gid] = 1.0f / sqrtf((float)max(degS[gid], 1));
    }
    if (gid == n - 1) row_ptr[n] = start + v;
}

__global__ __launch_bounds__(256) void k_scatter(
    const int* __restrict__ src, const int* __restrict__ dst,
    int* __restrict__ cursor, int* __restrict__ edge_src, int e)
{
    int gid = blockIdx.x * 256 + threadIdx.x;
    if (gid >= e) return;
    int pos = atomicAdd(&cursor[dst[gid]], 1);
    edge_src[pos] = src[gid];
}

// ---- GEMM1 via bf16 MFMA: Y[n][64] = (X[n][512] @ W1) * scale[row] ----
__global__ __launch_bounds__(256) void k_gemm1_mfma(
    const float* __restrict__ X, const short* __restrict__ w1f,
    const float* __restrict__ scale, float* __restrict__ Y, int n)
{
    const int tid  = threadIdx.x;
    const int l    = tid & 63;
    const int wv   = tid >> 6;
    const int row0 = blockIdx.x * 128 + wv * 32;
    const int lr   = l & 15;
    const int kg   = l >> 4;

    int ra0 = row0 + lr;       if (ra0 >= n) ra0 = n - 1;
    int ra1 = row0 + 16 + lr;  if (ra1 >= n) ra1 = n - 1;
    const float* pa0 = X + (size_t)ra0 * 512 + kg * 8;
    const float* pa1 = X + (size_t)ra1 * 512 + kg * 8;

    f32x4 acc[2][4];
#pragma unroll
    for (int i = 0; i < 2; ++i)
#pragma unroll
        for (int j = 0; j < 4; ++j) acc[i][j] = (f32x4){0.f, 0.f, 0.f, 0.f};

    float4 a0lo = *(const float4*)(pa0);
    float4 a0hi = *(const float4*)(pa0 + 4);
    float4 a1lo = *(const float4*)(pa1);
    float4 a1hi = *(const float4*)(pa1 + 4);

    for (int kt = 0; kt < 16; ++kt) {
        const short* pb = w1f + (size_t)(kt * 4) * 512 + l * 8;
        short8 b0 = *(const short8*)(pb);
        short8 b1 = *(const short8*)(pb + 512);
        short8 b2 = *(const short8*)(pb + 1024);
        short8 b3 = *(const short8*)(pb + 1536);

        short8 a0 = cvt8(a0lo, a0hi);
        short8 a1 = cvt8(a1lo, a1hi);

        if (kt < 15) {
            const float* q0 = pa0 + (kt + 1) * 32;
            const float* q1 = pa1 + (kt + 1) * 32;
            a0lo = *(const float4*)(q0);
            a0hi = *(const float4*)(q0 + 4);
            a1lo = *(const float4*)(q1);
            a1hi = *(const float4*)(q1 + 4);
        }

        acc[0][0] = __builtin_amdgcn_mfma_f32_16x16x32_bf16(a0, b0, acc[0][0], 0, 0, 0);
        acc[0][1] = __builtin_amdgcn_mfma_f32_16x16x32_bf16(a0, b1, acc[0][1], 0, 0, 0);
        acc[0][2] = __builtin_amdgcn_mfma_f32_16x16x32_bf16(a0, b2, acc[0][2], 0, 0, 0);
        acc[0][3] = __builtin_amdgcn_mfma_f32_16x16x32_bf16(a0, b3, acc[0][3], 0, 0, 0);
        acc[1][0] = __builtin_amdgcn_mfma_f32_16x16x32_bf16(a1, b0, acc[1][0], 0, 0, 0);
        acc[1][1] = __builtin_amdgcn_mfma_f32_16x16x32_bf16(a1, b1, acc[1][1], 0, 0, 0);
        acc[1][2] = __builtin_amdgcn_mfma_f32_16x16x32_bf16(a1, b2, acc[1][2], 0, 0, 0);
        acc[1][3] = __builtin_amdgcn_mfma_f32_16x16x32_bf16(a1, b3, acc[1][3], 0, 0, 0);
    }

#pragma unroll
    for (int mr = 0; mr < 2; ++mr) {
#pragma unroll
        for (int m = 0; m < 4; ++m) {
            int row = row0 + mr * 16 + kg * 4 + m;
            if (row < n) {
                float s = scale[row];
#pragma unroll
                for (int nt = 0; nt < 4; ++nt)
                    Y[(size_t)row * 64 + nt * 16 + lr] = acc[mr][nt][m] * s;
            }
        }
    }
}

// ---- GEMM23 f32 (K=64): t23 = h @ wc ----
__global__ __launch_bounds__(256) void k_gemm2(
    const float* __restrict__ X, const float* __restrict__ W,
    float* __restrict__ Y, int n)
{
    __shared__ float sx[64][68];
    __shared__ float sw[64][64];
    const int tid  = threadIdx.x;
    const int colp = tid & 31;
    const int rg   = tid >> 5;
    const int row0 = blockIdx.x * 64;

    float2 acc[8];
#pragma unroll
    for (int i = 0; i < 8; ++i) acc[i] = make_float2(0.f, 0.f);

#pragma unroll
    for (int p = 0; p < 4; ++p) {
        int u = p * 256 + tid;
        int r = u >> 4, c4 = (u & 15) * 4;
        int row = row0 + r;
        float4 v = make_float4(0.f, 0.f, 0.f, 0.f);
        if (row < n) v = *(const float4*)&X[(size_t)row * 64 + c4];
        *(float4*)&sx[r][c4] = v;
        *(float4*)&sw[r][c4] = *(const float4*)&W[u * 4];
    }
    __syncthreads();

#pragma unroll 4
    for (int k4 = 0; k4 < 64; k4 += 4) {
        float2 w0 = *(const float2*)&sw[k4 + 0][colp * 2];
        float2 w1 = *(const float2*)&sw[k4 + 1][colp * 2];
        float2 w2 = *(const float2*)&sw[k4 + 2][colp * 2];
        float2 w3 = *(const float2*)&sw[k4 + 3][colp * 2];
#pragma unroll
        for (int i = 0; i < 8; ++i) {
            float4 f = *(const float4*)&sx[rg * 8 + i][k4];
            acc[i].x += f.x * w0.x + f.y * w1.x + f.z * w2.x + f.w * w3.x;
            acc[i].y += f.x * w0.y + f.y * w1.y + f.z * w2.y + f.w * w3.y;
        }
    }

#pragma unroll
    for (int i = 0; i < 8; ++i) {
        int row = row0 + rg * 8 + i;
        if (row < n)
            *(float2*)&Y[(size_t)row * 64 + colp * 2] =
                make_float2(acc[i].x, acc[i].y);
    }
}

// ---- gather SPMM 1: h = relu(sum * isq_in + b1) * isq_out ----
__global__ __launch_bounds__(256) void k_gather_h(
    const int* __restrict__ row_ptr, const int* __restrict__ edge_src,
    const float* __restrict__ x, const float* __restrict__ isq_in,
    const float* __restrict__ isq_out, const float* __restrict__ b1,
    float* __restrict__ h, int n)
{
    int col  = threadIdx.x & 63;
    int node = __builtin_amdgcn_readfirstlane(blockIdx.x * 4 + (threadIdx.x >> 6));
    if (node >= n) return;
    int j = row_ptr[node], jend = row_ptr[node + 1];
    float a0 = 0.f, a1 = 0.f, a2 = 0.f, a3 = 0.f;
    for (; j + 3 < jend; j += 4) {
        int e0 = edge_src[j], e1 = edge_src[j + 1];
        int e2 = edge_src[j + 2], e3 = edge_src[j + 3];
        a0 += x[(size_t)e0 * 64 + col];
        a1 += x[(size_t)e1 * 64 + col];
        a2 += x[(size_t)e2 * 64 + col];
        a3 += x[(size_t)e3 * 64 + col];
    }
    for (; j < jend; ++j) a0 += x[(size_t)edge_src[j] * 64 + col];
    float acc = (a0 + a1) + (a2 + a3);
    h[(size_t)node * 64 + col] =
        fmaxf(acc * isq_in[node] + b1[col], 0.f) * isq_out[node];
}

// ---- gather SPMM 2 fused with final: out = [z | mean | log_std] ----
__global__ __launch_bounds__(256) void k_gather_final(
    const int* __restrict__ row_ptr, const int* __restrict__ edge_src,
    const float* __restrict__ t23, const float* __restrict__ isq_in,
    const float* __restrict__ b2, const float* __restrict__ b3,
    const float* __restrict__ noise, float* __restrict__ out, int n)
{
    int lane = threadIdx.x & 63;
    int node = __builtin_amdgcn_readfirstlane(blockIdx.x * 4 + (threadIdx.x >> 6));
    if (node >= n) return;
    int j = row_ptr[node], jend = row_ptr[node + 1];
    float a0 = 0.f, a1 = 0.f, a2 = 0.f, a3 = 0.f;
    for (; j + 3 < jend; j += 4) {
        int e0 = edge_src[j], e1 = edge_src[j + 1];
        int e2 = edge_src[j + 2], e3 = edge_src[j + 3];
        a0 += t23[(size_t)e0 * 64 + lane];
        a1 += t23[(size_t)e1 * 64 + lane];
        a2 += t23[(size_t)e2 * 64 + lane];
        a3 += t23[(size_t)e3 * 64 + lane];
    }
    for (; j < jend; ++j) a0 += t23[(size_t)edge_src[j] * 64 + lane];
    float acc = (a0 + a1) + (a2 + a3);
    float si = isq_in[node];
    float v  = acc * si + (lane < 32 ? b2[lane] : b3[lane - 32]);
    float lv = __shfl(v, lane | 32, 64);
    int total = n * 32;
    int base  = node * 32 + (lane & 31);
    if (lane < 32) {
        float z = v + noise[base] * expf(lv);
        out[base]         = z;
        out[total + base] = v;
    } else {
        out[2 * total + base] = v;
    }
}

extern "C" void kernel_launch(void* const* d_in, const int* in_sizes, int n_in,
                              void* d_out, int out_size, void* d_ws, size_t ws_size,
                              hipStream_t stream)
{
    const float* feat  = (const float*)d_in[0];
    const int*   src   = (const int*)d_in[1];
    const int*   dst   = (const int*)d_in[2];
    const float* noise = (const float*)d_in[3];
    const float* W1    = (const float*)d_in[4];
    const float* b1    = (const float*)d_in[5];
    const float* W2    = (const float*)d_in[6];
    const float* b2    = (const float*)d_in[7];
    const float* W3    = (const float*)d_in[8];
    const float* b3    = (const float*)d_in[9];

    const int n = in_sizes[0] / 512;
    const int e = in_sizes[1];

    float* ws      = (float*)d_ws;
    float* isq_out = ws;
    float* isq_in  = ws + n;
    float* bufA    = ws + 2 * (size_t)n;
    float* bufB    = bufA + 64 * (size_t)n;
    float* wc      = bufB + 64 * (size_t)n;            // 4096 f32
    short* w1f     = (short*)(wc + 64 * 64);           // 32768 shorts
    int*   ip      = (int*)(w1f + 512 * 64);
    int* row_ptr   = ip;
    int* cursor    = ip + (n + 1);
    int* partials  = cursor + n;
    int* edge_src  = partials + 512;
    int* degS = (int*)bufA;                            // transient overlay
    int* degD = degS + n;
    float* out = (float*)d_out;

    const int nb = (n + 255) / 256;

    // zero degree histograms (2n ints) with a plain kernel, NOT hipMemsetAsync
    // (the graph-captured rocclr fill node measured ~115us for 800KB).
    const int z4 = (2 * n) / 4;   // n divisible by 4 here (100000)
    k_zero<<<(z4 + 255) / 256, 256, 0, stream>>>((int4*)degS, z4);

    k_build_wc<<<(64 * 64 + 255) / 256, 256, 0, stream>>>(W2, W3, wc);
    k_pack_w1<<<(512 * 64 + 255) / 256, 256, 0, stream>>>(W1, w1f);
    k_deg_int<<<(e + 255) / 256, 256, 0, stream>>>(src, dst, degS, degD, e);

    k_scan_block_sums<<<nb, 256, 0, stream>>>(degD, partials, n);
    k_scan_partials<<<1, 512, 0, stream>>>(partials, nb);
    k_scan_final<<<nb, 256, 0, stream>>>(
        degD, degS, partials, row_ptr, cursor, isq_out, isq_in, n);
    k_scatter<<<(e + 255) / 256, 256, 0, stream>>>(src, dst, cursor, edge_src, e);

    k_gemm1_mfma<<<(n + 127) / 128, 256, 0, stream>>>(
        feat, w1f, isq_out, bufA, n);

    k_gather_h<<<(n + 3) / 4, 256, 0, stream>>>(
        row_ptr, edge_src, bufA, isq_in, isq_out, b1, bufB, n);

    k_gemm2<<<(n + 63) / 64, 256, 0, stream>>>(bufB, wc, bufA, n);

    k_gather_final<<<(n + 3) / 4, 256, 0, stream>>>(
        row_ptr, edge_src, bufA, isq_in, b2, b3, noise, out, n);
}

// Round 6
// 282.038 us; speedup vs baseline: 1.0855x; 1.0855x over previous
//
#include <hip/hip_runtime.h>
#include <hip/hip_bf16.h>

// ---------------------------------------------------------------------------
// VGAE forward, round 6:
//  - gemm1: bf16 MFMA, A AND B software-prefetched (B chain was unhidden),
//    h_pre written as bf16 (gather payload).
//  - gathers: bf16 payloads (128B/edge), 8-deep unroll (MLP).
//  - t23 stored bf16; all accumulation f32.
//  - setup kernels merged (zero + pack_w1 + build_wc).
//
// d_ws layout:
//   isq_out [n], isq_in [n]
//   bufA [64n f32 worth] : degS/degD overlay -> h_pre (bf16) -> t23 (bf16)
//   bufB [64n f32]       : h (gather1 out, f32, gemm2 in)
//   wc   [64*64 f32]     : [W2|W3] combined, natural [k][col]
//   w1f  [32768 shorts]  : W1 bf16 MFMA-fragment-linear
//   ints: row_ptr[n+1], cursor[n], partials[512], edge_src[e]
// ---------------------------------------------------------------------------

typedef __attribute__((ext_vector_type(8))) short short8;
typedef __attribute__((ext_vector_type(4))) float f32x4;
typedef unsigned short ushort_t;

static __device__ inline short f2bf(float f)
{
    union { __hip_bfloat16 h; short s; } u;
    u.h = __float2bfloat16(f);
    return u.s;
}

static __device__ inline float bf2f(ushort_t u)
{
    union { float f; unsigned v; } w;
    w.v = ((unsigned)u) << 16;
    return w.f;
}

static __device__ inline short8 cvt8(float4 lo, float4 hi)
{
    short8 r;
    r[0] = f2bf(lo.x); r[1] = f2bf(lo.y); r[2] = f2bf(lo.z); r[3] = f2bf(lo.w);
    r[4] = f2bf(hi.x); r[5] = f2bf(hi.y); r[6] = f2bf(hi.z); r[7] = f2bf(hi.w);
    return r;
}

// ---- merged setup: zero degree hist, build wc, pack w1 ----
__global__ __launch_bounds__(256) void k_setup(
    const float* __restrict__ W1, const float* __restrict__ W2,
    const float* __restrict__ W3, short* __restrict__ w1f,
    float* __restrict__ wc, int4* __restrict__ zp, int z4)
{
    int gid = blockIdx.x * 256 + threadIdx.x;
    if (gid < z4) zp[gid] = make_int4(0, 0, 0, 0);
    if (gid < 64 * 64) {
        int k = gid >> 6, c = gid & 63;
        wc[gid] = (c < 32) ? W2[k * 32 + c] : W3[k * 32 + (c - 32)];
    }
    if (gid < 512 * 64) {
        int k = gid >> 6, c = gid & 63;
        int kt = k >> 5, kk = k & 31, nt = c >> 4, lr = c & 15;
        int kg = kk >> 3, j = kk & 7;
        int l = kg * 16 + lr;
        w1f[(kt * 4 + nt) * 512 + l * 8 + j] = f2bf(W1[gid]);
    }
}

__global__ __launch_bounds__(256) void k_deg_int(
    const int* __restrict__ src, const int* __restrict__ dst,
    int* __restrict__ degS, int* __restrict__ degD, int e)
{
    int gid = blockIdx.x * 256 + threadIdx.x;
    if (gid >= e) return;
    atomicAdd(&degS[src[gid]], 1);
    atomicAdd(&degD[dst[gid]], 1);
}

__global__ __launch_bounds__(256) void k_scan_block_sums(
    const int* __restrict__ deg, int* __restrict__ partials, int n)
{
    __shared__ int red[256];
    int gid = blockIdx.x * 256 + threadIdx.x;
    red[threadIdx.x] = (gid < n) ? deg[gid] : 0;
    __syncthreads();
    for (int s = 128; s > 0; s >>= 1) {
        if (threadIdx.x < s) red[threadIdx.x] += red[threadIdx.x + s];
        __syncthreads();
    }
    if (threadIdx.x == 0) partials[blockIdx.x] = red[0];
}

__global__ __launch_bounds__(512) void k_scan_partials(
    int* __restrict__ partials, int nb)
{
    __shared__ int s[512];
    int t = threadIdx.x;
    s[t] = (t < nb) ? partials[t] : 0;
    __syncthreads();
    for (int d = 1; d < 512; d <<= 1) {
        int v = (t >= d) ? s[t - d] : 0;
        __syncthreads();
        s[t] += v;
        __syncthreads();
    }
    if (t < nb) partials[t] = (t == 0) ? 0 : s[t - 1];
}

__global__ __launch_bounds__(256) void k_scan_final(
    const int* __restrict__ degD, const int* __restrict__ degS,
    const int* __restrict__ partials,
    int* __restrict__ row_ptr, int* __restrict__ cursor,
    float* __restrict__ isq_out, float* __restrict__ isq_in, int n)
{
    __shared__ int s[256];
    int t = threadIdx.x;
    int gid = blockIdx.x * 256 + t;
    int v = (gid < n) ? degD[gid] : 0;
    s[t] = v;
    __syncthreads();
    for (int d = 1; d < 256; d <<= 1) {
        int u = (t >= d) ? s[t - d] : 0;
        __syncthreads();
        s[t] += u;
        __syncthreads();
    }
    int start = partials[blockIdx.x] + s[t] - v;
    if (gid < n) {
        row_ptr[gid] = start;
        cursor[gid]  = start;
        isq_in[gid]  = 1.0f / sqrtf((float)max(v, 1));
        isq_out[gid] = 1.0f / sqrtf((float)max(degS[gid], 1));
    }
    if (gid == n - 1) row_ptr[n] = start + v;
}

__global__ __launch_bounds__(256) void k_scatter(
    const int* __restrict__ src, const int* __restrict__ dst,
    int* __restrict__ cursor, int* __restrict__ edge_src, int e)
{
    int gid = blockIdx.x * 256 + threadIdx.x;
    if (gid >= e) return;
    int pos = atomicAdd(&cursor[dst[gid]], 1);
    edge_src[pos] = src[gid];
}

// ---- GEMM1 bf16 MFMA: h_pre[n][64] (bf16) = (X @ W1) * scale[row] ----
// A and B both prefetched one kt step ahead.
__global__ __launch_bounds__(256) void k_gemm1_mfma(
    const float* __restrict__ X, const short* __restrict__ w1f,
    const float* __restrict__ scale, ushort_t* __restrict__ Y, int n)
{
    const int tid  = threadIdx.x;
    const int l    = tid & 63;
    const int wv   = tid >> 6;
    const int row0 = blockIdx.x * 128 + wv * 32;
    const int lr   = l & 15;
    const int kg   = l >> 4;

    int ra0 = row0 + lr;       if (ra0 >= n) ra0 = n - 1;
    int ra1 = row0 + 16 + lr;  if (ra1 >= n) ra1 = n - 1;
    const float* pa0 = X + (size_t)ra0 * 512 + kg * 8;
    const float* pa1 = X + (size_t)ra1 * 512 + kg * 8;
    const short* pb  = w1f + l * 8;

    f32x4 acc[2][4];
#pragma unroll
    for (int i = 0; i < 2; ++i)
#pragma unroll
        for (int j = 0; j < 4; ++j) acc[i][j] = (f32x4){0.f, 0.f, 0.f, 0.f};

    // prefetch kt=0: A and B
    float4 a0lo = *(const float4*)(pa0);
    float4 a0hi = *(const float4*)(pa0 + 4);
    float4 a1lo = *(const float4*)(pa1);
    float4 a1hi = *(const float4*)(pa1 + 4);
    short8 b0 = *(const short8*)(pb);
    short8 b1 = *(const short8*)(pb + 512);
    short8 b2 = *(const short8*)(pb + 1024);
    short8 b3 = *(const short8*)(pb + 1536);

    for (int kt = 0; kt < 16; ++kt) {
        short8 ca0 = cvt8(a0lo, a0hi);
        short8 ca1 = cvt8(a1lo, a1hi);
        short8 cb0 = b0, cb1 = b1, cb2 = b2, cb3 = b3;

        if (kt < 15) {   // issue next-step A+B loads before the MFMAs
            const float* q0 = pa0 + (kt + 1) * 32;
            const float* q1 = pa1 + (kt + 1) * 32;
            a0lo = *(const float4*)(q0);
            a0hi = *(const float4*)(q0 + 4);
            a1lo = *(const float4*)(q1);
            a1hi = *(const float4*)(q1 + 4);
            const short* q = pb + (size_t)(kt + 1) * 2048;
            b0 = *(const short8*)(q);
            b1 = *(const short8*)(q + 512);
            b2 = *(const short8*)(q + 1024);
            b3 = *(const short8*)(q + 1536);
        }

        acc[0][0] = __builtin_amdgcn_mfma_f32_16x16x32_bf16(ca0, cb0, acc[0][0], 0, 0, 0);
        acc[0][1] = __builtin_amdgcn_mfma_f32_16x16x32_bf16(ca0, cb1, acc[0][1], 0, 0, 0);
        acc[0][2] = __builtin_amdgcn_mfma_f32_16x16x32_bf16(ca0, cb2, acc[0][2], 0, 0, 0);
        acc[0][3] = __builtin_amdgcn_mfma_f32_16x16x32_bf16(ca0, cb3, acc[0][3], 0, 0, 0);
        acc[1][0] = __builtin_amdgcn_mfma_f32_16x16x32_bf16(ca1, cb0, acc[1][0], 0, 0, 0);
        acc[1][1] = __builtin_amdgcn_mfma_f32_16x16x32_bf16(ca1, cb1, acc[1][1], 0, 0, 0);
        acc[1][2] = __builtin_amdgcn_mfma_f32_16x16x32_bf16(ca1, cb2, acc[1][2], 0, 0, 0);
        acc[1][3] = __builtin_amdgcn_mfma_f32_16x16x32_bf16(ca1, cb3, acc[1][3], 0, 0, 0);
    }

#pragma unroll
    for (int mr = 0; mr < 2; ++mr) {
#pragma unroll
        for (int m = 0; m < 4; ++m) {
            int row = row0 + mr * 16 + kg * 4 + m;
            if (row < n) {
                float s = scale[row];
#pragma unroll
                for (int nt = 0; nt < 4; ++nt)
                    Y[(size_t)row * 64 + nt * 16 + lr] =
                        (ushort_t)f2bf(acc[mr][nt][m] * s);
            }
        }
    }
}

// ---- gather SPMM 1 (bf16 payload): h = relu(sum*isq_in + b1)*isq_out ----
__global__ __launch_bounds__(256) void k_gather_h(
    const int* __restrict__ row_ptr, const int* __restrict__ edge_src,
    const ushort_t* __restrict__ x, const float* __restrict__ isq_in,
    const float* __restrict__ isq_out, const float* __restrict__ b1,
    float* __restrict__ h, int n)
{
    int col  = threadIdx.x & 63;
    int node = __builtin_amdgcn_readfirstlane(blockIdx.x * 4 + (threadIdx.x >> 6));
    if (node >= n) return;
    int j = row_ptr[node], jend = row_ptr[node + 1];
    float a0 = 0.f, a1 = 0.f, a2 = 0.f, a3 = 0.f;
    float a4 = 0.f, a5 = 0.f, a6 = 0.f, a7 = 0.f;
    for (; j + 7 < jend; j += 8) {
        int e0 = edge_src[j],     e1 = edge_src[j + 1];
        int e2 = edge_src[j + 2], e3 = edge_src[j + 3];
        int e4 = edge_src[j + 4], e5 = edge_src[j + 5];
        int e6 = edge_src[j + 6], e7 = edge_src[j + 7];
        a0 += bf2f(x[(size_t)e0 * 64 + col]);
        a1 += bf2f(x[(size_t)e1 * 64 + col]);
        a2 += bf2f(x[(size_t)e2 * 64 + col]);
        a3 += bf2f(x[(size_t)e3 * 64 + col]);
        a4 += bf2f(x[(size_t)e4 * 64 + col]);
        a5 += bf2f(x[(size_t)e5 * 64 + col]);
        a6 += bf2f(x[(size_t)e6 * 64 + col]);
        a7 += bf2f(x[(size_t)e7 * 64 + col]);
    }
    for (; j + 1 < jend; j += 2) {
        int e0 = edge_src[j], e1 = edge_src[j + 1];
        a0 += bf2f(x[(size_t)e0 * 64 + col]);
        a1 += bf2f(x[(size_t)e1 * 64 + col]);
    }
    if (j < jend) a2 += bf2f(x[(size_t)edge_src[j] * 64 + col]);
    float acc = ((a0 + a1) + (a2 + a3)) + ((a4 + a5) + (a6 + a7));
    h[(size_t)node * 64 + col] =
        fmaxf(acc * isq_in[node] + b1[col], 0.f) * isq_out[node];
}

// ---- GEMM23 f32 (K=64): t23 (bf16) = h @ wc ----
__global__ __launch_bounds__(256) void k_gemm2(
    const float* __restrict__ X, const float* __restrict__ W,
    ushort_t* __restrict__ Y, int n)
{
    __shared__ float sx[64][68];
    __shared__ float sw[64][64];
    const int tid  = threadIdx.x;
    const int colp = tid & 31;
    const int rg   = tid >> 5;
    const int row0 = blockIdx.x * 64;

    float2 acc[8];
#pragma unroll
    for (int i = 0; i < 8; ++i) acc[i] = make_float2(0.f, 0.f);

#pragma unroll
    for (int p = 0; p < 4; ++p) {
        int u = p * 256 + tid;
        int r = u >> 4, c4 = (u & 15) * 4;
        int row = row0 + r;
        float4 v = make_float4(0.f, 0.f, 0.f, 0.f);
        if (row < n) v = *(const float4*)&X[(size_t)row * 64 + c4];
        *(float4*)&sx[r][c4] = v;
        *(float4*)&sw[r][c4] = *(const float4*)&W[u * 4];
    }
    __syncthreads();

#pragma unroll 4
    for (int k4 = 0; k4 < 64; k4 += 4) {
        float2 w0 = *(const float2*)&sw[k4 + 0][colp * 2];
        float2 w1 = *(const float2*)&sw[k4 + 1][colp * 2];
        float2 w2 = *(const float2*)&sw[k4 + 2][colp * 2];
        float2 w3 = *(const float2*)&sw[k4 + 3][colp * 2];
#pragma unroll
        for (int i = 0; i < 8; ++i) {
            float4 f = *(const float4*)&sx[rg * 8 + i][k4];
            acc[i].x += f.x * w0.x + f.y * w1.x + f.z * w2.x + f.w * w3.x;
            acc[i].y += f.x * w0.y + f.y * w1.y + f.z * w2.y + f.w * w3.y;
        }
    }

#pragma unroll
    for (int i = 0; i < 8; ++i) {
        int row = row0 + rg * 8 + i;
        if (row < n) {
            unsigned lo = (unsigned)(unsigned short)f2bf(acc[i].x);
            unsigned hi = (unsigned)(unsigned short)f2bf(acc[i].y);
            ((unsigned*)Y)[(size_t)row * 32 + colp] = (hi << 16) | lo;
        }
    }
}

// ---- gather SPMM 2 (bf16 payload) + final: out = [z | mean | log_std] ----
__global__ __launch_bounds__(256) void k_gather_final(
    const int* __restrict__ row_ptr, const int* __restrict__ edge_src,
    const ushort_t* __restrict__ t23, const float* __restrict__ isq_in,
    const float* __restrict__ b2, const float* __restrict__ b3,
    const float* __restrict__ noise, float* __restrict__ out, int n)
{
    int lane = threadIdx.x & 63;
    int node = __builtin_amdgcn_readfirstlane(blockIdx.x * 4 + (threadIdx.x >> 6));
    if (node >= n) return;
    int j = row_ptr[node], jend = row_ptr[node + 1];
    float a0 = 0.f, a1 = 0.f, a2 = 0.f, a3 = 0.f;
    float a4 = 0.f, a5 = 0.f, a6 = 0.f, a7 = 0.f;
    for (; j + 7 < jend; j += 8) {
        int e0 = edge_src[j],     e1 = edge_src[j + 1];
        int e2 = edge_src[j + 2], e3 = edge_src[j + 3];
        int e4 = edge_src[j + 4], e5 = edge_src[j + 5];
        int e6 = edge_src[j + 6], e7 = edge_src[j + 7];
        a0 += bf2f(t23[(size_t)e0 * 64 + lane]);
        a1 += bf2f(t23[(size_t)e1 * 64 + lane]);
        a2 += bf2f(t23[(size_t)e2 * 64 + lane]);
        a3 += bf2f(t23[(size_t)e3 * 64 + lane]);
        a4 += bf2f(t23[(size_t)e4 * 64 + lane]);
        a5 += bf2f(t23[(size_t)e5 * 64 + lane]);
        a6 += bf2f(t23[(size_t)e6 * 64 + lane]);
        a7 += bf2f(t23[(size_t)e7 * 64 + lane]);
    }
    for (; j + 1 < jend; j += 2) {
        int e0 = edge_src[j], e1 = edge_src[j + 1];
        a0 += bf2f(t23[(size_t)e0 * 64 + lane]);
        a1 += bf2f(t23[(size_t)e1 * 64 + lane]);
    }
    if (j < jend) a2 += bf2f(t23[(size_t)edge_src[j] * 64 + lane]);
    float acc = ((a0 + a1) + (a2 + a3)) + ((a4 + a5) + (a6 + a7));
    float si = isq_in[node];
    float v  = acc * si + (lane < 32 ? b2[lane] : b3[lane - 32]);
    float lv = __shfl(v, lane | 32, 64);
    int total = n * 32;
    int base  = node * 32 + (lane & 31);
    if (lane < 32) {
        float z = v + noise[base] * expf(lv);
        out[base]         = z;
        out[total + base] = v;
    } else {
        out[2 * total + base] = v;
    }
}

extern "C" void kernel_launch(void* const* d_in, const int* in_sizes, int n_in,
                              void* d_out, int out_size, void* d_ws, size_t ws_size,
                              hipStream_t stream)
{
    const float* feat  = (const float*)d_in[0];
    const int*   src   = (const int*)d_in[1];
    const int*   dst   = (const int*)d_in[2];
    const float* noise = (const float*)d_in[3];
    const float* W1    = (const float*)d_in[4];
    const float* b1    = (const float*)d_in[5];
    const float* W2    = (const float*)d_in[6];
    const float* b2    = (const float*)d_in[7];
    const float* W3    = (const float*)d_in[8];
    const float* b3    = (const float*)d_in[9];

    const int n = in_sizes[0] / 512;
    const int e = in_sizes[1];

    float* ws      = (float*)d_ws;
    float* isq_out = ws;
    float* isq_in  = ws + n;
    float* bufA    = ws + 2 * (size_t)n;               // h_pre/t23 (bf16)
    float* bufB    = bufA + 64 * (size_t)n;            // h (f32)
    float* wc      = bufB + 64 * (size_t)n;            // 4096 f32
    short* w1f     = (short*)(wc + 64 * 64);           // 32768 shorts
    int*   ip      = (int*)(w1f + 512 * 64);
    int* row_ptr   = ip;
    int* cursor    = ip + (n + 1);
    int* partials  = cursor + n;
    int* edge_src  = partials + 512;
    int* degS = (int*)bufA;                            // transient overlay
    int* degD = degS + n;
    float* out = (float*)d_out;

    const int nb = (n + 255) / 256;
    const int z4 = (2 * n) / 4;

    k_setup<<<(z4 + 255) / 256, 256, 0, stream>>>(
        W1, W2, W3, w1f, wc, (int4*)degS, z4);

    k_deg_int<<<(e + 255) / 256, 256, 0, stream>>>(src, dst, degS, degD, e);

    k_scan_block_sums<<<nb, 256, 0, stream>>>(degD, partials, n);
    k_scan_partials<<<1, 512, 0, stream>>>(partials, nb);
    k_scan_final<<<nb, 256, 0, stream>>>(
        degD, degS, partials, row_ptr, cursor, isq_out, isq_in, n);
    k_scatter<<<(e + 255) / 256, 256, 0, stream>>>(src, dst, cursor, edge_src, e);

    k_gemm1_mfma<<<(n + 127) / 128, 256, 0, stream>>>(
        feat, w1f, isq_out, (ushort_t*)bufA, n);

    k_gather_h<<<(n + 3) / 4, 256, 0, stream>>>(
        row_ptr, edge_src, (const ushort_t*)bufA, isq_in, isq_out, b1, bufB, n);

    k_gemm2<<<(n + 63) / 64, 256, 0, stream>>>(bufB, wc, (ushort_t*)bufA, n);

    k_gather_final<<<(n + 3) / 4, 256, 0, stream>>>(
        row_ptr, edge_src, (const ushort_t*)bufA, isq_in, b2, b3, noise, out, n);
}

// Round 7
// 266.434 us; speedup vs baseline: 1.1491x; 1.0586x over previous
//
#include <hip/hip_runtime.h>
#include <hip/hip_bf16.h>

// ---------------------------------------------------------------------------
// VGAE forward, round 7:
//  - gemm1: 16 rows/wave (2x waves vs r6), A-prefetch depth 2, B depth 1,
//    fully unrolled kt loop (static stage indices). Targets latency-bound gap.
//  - gathers: epilogue loads hoisted above the gather loop.
//  - everything else as round 6.
//
// d_ws layout:
//   isq_out [n], isq_in [n]
//   bufA [64n f32 worth] : degS/degD overlay -> h_pre (bf16) -> t23 (bf16)
//   bufB [64n f32]       : h (gather1 out, f32, gemm2 in)
//   wc   [64*64 f32]     : [W2|W3] combined, natural [k][col]
//   w1f  [32768 shorts]  : W1 bf16 MFMA-fragment-linear
//   ints: row_ptr[n+1], cursor[n], partials[512], edge_src[e]
// ---------------------------------------------------------------------------

typedef __attribute__((ext_vector_type(8))) short short8;
typedef __attribute__((ext_vector_type(4))) float f32x4;
typedef unsigned short ushort_t;

static __device__ inline short f2bf(float f)
{
    union { __hip_bfloat16 h; short s; } u;
    u.h = __float2bfloat16(f);
    return u.s;
}

static __device__ inline float bf2f(ushort_t u)
{
    union { float f; unsigned v; } w;
    w.v = ((unsigned)u) << 16;
    return w.f;
}

static __device__ inline short8 cvt8(float4 lo, float4 hi)
{
    short8 r;
    r[0] = f2bf(lo.x); r[1] = f2bf(lo.y); r[2] = f2bf(lo.z); r[3] = f2bf(lo.w);
    r[4] = f2bf(hi.x); r[5] = f2bf(hi.y); r[6] = f2bf(hi.z); r[7] = f2bf(hi.w);
    return r;
}

// ---- merged setup: zero degree hist, build wc, pack w1 ----
__global__ __launch_bounds__(256) void k_setup(
    const float* __restrict__ W1, const float* __restrict__ W2,
    const float* __restrict__ W3, short* __restrict__ w1f,
    float* __restrict__ wc, int4* __restrict__ zp, int z4)
{
    int gid = blockIdx.x * 256 + threadIdx.x;
    if (gid < z4) zp[gid] = make_int4(0, 0, 0, 0);
    if (gid < 64 * 64) {
        int k = gid >> 6, c = gid & 63;
        wc[gid] = (c < 32) ? W2[k * 32 + c] : W3[k * 32 + (c - 32)];
    }
    if (gid < 512 * 64) {
        int k = gid >> 6, c = gid & 63;
        int kt = k >> 5, kk = k & 31, nt = c >> 4, lr = c & 15;
        int kg = kk >> 3, j = kk & 7;
        int l = kg * 16 + lr;
        w1f[(kt * 4 + nt) * 512 + l * 8 + j] = f2bf(W1[gid]);
    }
}

__global__ __launch_bounds__(256) void k_deg_int(
    const int* __restrict__ src, const int* __restrict__ dst,
    int* __restrict__ degS, int* __restrict__ degD, int e)
{
    int gid = blockIdx.x * 256 + threadIdx.x;
    if (gid >= e) return;
    atomicAdd(&degS[src[gid]], 1);
    atomicAdd(&degD[dst[gid]], 1);
}

__global__ __launch_bounds__(256) void k_scan_block_sums(
    const int* __restrict__ deg, int* __restrict__ partials, int n)
{
    __shared__ int red[256];
    int gid = blockIdx.x * 256 + threadIdx.x;
    red[threadIdx.x] = (gid < n) ? deg[gid] : 0;
    __syncthreads();
    for (int s = 128; s > 0; s >>= 1) {
        if (threadIdx.x < s) red[threadIdx.x] += red[threadIdx.x + s];
        __syncthreads();
    }
    if (threadIdx.x == 0) partials[blockIdx.x] = red[0];
}

__global__ __launch_bounds__(512) void k_scan_partials(
    int* __restrict__ partials, int nb)
{
    __shared__ int s[512];
    int t = threadIdx.x;
    s[t] = (t < nb) ? partials[t] : 0;
    __syncthreads();
    for (int d = 1; d < 512; d <<= 1) {
        int v = (t >= d) ? s[t - d] : 0;
        __syncthreads();
        s[t] += v;
        __syncthreads();
    }
    if (t < nb) partials[t] = (t == 0) ? 0 : s[t - 1];
}

__global__ __launch_bounds__(256) void k_scan_final(
    const int* __restrict__ degD, const int* __restrict__ degS,
    const int* __restrict__ partials,
    int* __restrict__ row_ptr, int* __restrict__ cursor,
    float* __restrict__ isq_out, float* __restrict__ isq_in, int n)
{
    __shared__ int s[256];
    int t = threadIdx.x;
    int gid = blockIdx.x * 256 + t;
    int v = (gid < n) ? degD[gid] : 0;
    s[t] = v;
    __syncthreads();
    for (int d = 1; d < 256; d <<= 1) {
        int u = (t >= d) ? s[t - d] : 0;
        __syncthreads();
        s[t] += u;
        __syncthreads();
    }
    int start = partials[blockIdx.x] + s[t] - v;
    if (gid < n) {
        row_ptr[gid] = start;
        cursor[gid]  = start;
        isq_in[gid]  = 1.0f / sqrtf((float)max(v, 1));
        isq_out[gid] = 1.0f / sqrtf((float)max(degS[gid], 1));
    }
    if (gid == n - 1) row_ptr[n] = start + v;
}

__global__ __launch_bounds__(256) void k_scatter(
    const int* __restrict__ src, const int* __restrict__ dst,
    int* __restrict__ cursor, int* __restrict__ edge_src, int e)
{
    int gid = blockIdx.x * 256 + threadIdx.x;
    if (gid >= e) return;
    int pos = atomicAdd(&cursor[dst[gid]], 1);
    edge_src[pos] = src[gid];
}

// ---- GEMM1 bf16 MFMA: h_pre[n][64] (bf16) = (X @ W1) * scale[row] ----
// 16 rows per wave (M=1 tile), A prefetched 2 kt ahead, B 1 kt ahead.
__global__ __launch_bounds__(256) void k_gemm1_mfma(
    const float* __restrict__ X, const short* __restrict__ w1f,
    const float* __restrict__ scale, ushort_t* __restrict__ Y, int n)
{
    const int tid  = threadIdx.x;
    const int l    = tid & 63;
    const int wv   = tid >> 6;
    const int row0 = (blockIdx.x * 4 + wv) * 16;
    const int lr   = l & 15;
    const int kg   = l >> 4;

    int ra = row0 + lr;  if (ra >= n) ra = n - 1;
    const float* pa = X + (size_t)ra * 512 + kg * 8;
    const short* pb = w1f + l * 8;

    f32x4 acc[4];
#pragma unroll
    for (int j = 0; j < 4; ++j) acc[j] = (f32x4){0.f, 0.f, 0.f, 0.f};

    // A stages (depth 2), B stage (depth 1)
    float4 alo0 = *(const float4*)(pa);
    float4 ahi0 = *(const float4*)(pa + 4);
    float4 alo1 = *(const float4*)(pa + 32);
    float4 ahi1 = *(const float4*)(pa + 36);
    short8 b0 = *(const short8*)(pb);
    short8 b1 = *(const short8*)(pb + 512);
    short8 b2 = *(const short8*)(pb + 1024);
    short8 b3 = *(const short8*)(pb + 1536);

#pragma unroll
    for (int kt = 0; kt < 16; ++kt) {
        short8 ca = (kt & 1) ? cvt8(alo1, ahi1) : cvt8(alo0, ahi0);
        if (kt + 2 < 16) {          // refill the stage just consumed
            const float* q = pa + (kt + 2) * 32;
            if (kt & 1) { alo1 = *(const float4*)(q); ahi1 = *(const float4*)(q + 4); }
            else        { alo0 = *(const float4*)(q); ahi0 = *(const float4*)(q + 4); }
        }
        short8 cb0 = b0, cb1 = b1, cb2 = b2, cb3 = b3;
        if (kt + 1 < 16) {
            const short* q = pb + (size_t)(kt + 1) * 2048;
            b0 = *(const short8*)(q);
            b1 = *(const short8*)(q + 512);
            b2 = *(const short8*)(q + 1024);
            b3 = *(const short8*)(q + 1536);
        }
        acc[0] = __builtin_amdgcn_mfma_f32_16x16x32_bf16(ca, cb0, acc[0], 0, 0, 0);
        acc[1] = __builtin_amdgcn_mfma_f32_16x16x32_bf16(ca, cb1, acc[1], 0, 0, 0);
        acc[2] = __builtin_amdgcn_mfma_f32_16x16x32_bf16(ca, cb2, acc[2], 0, 0, 0);
        acc[3] = __builtin_amdgcn_mfma_f32_16x16x32_bf16(ca, cb3, acc[3], 0, 0, 0);
    }

    // D: lane l holds D[kg*4 + m][lr] for each N-tile nt
#pragma unroll
    for (int m = 0; m < 4; ++m) {
        int row = row0 + kg * 4 + m;
        if (row < n) {
            float s = scale[row];
#pragma unroll
            for (int nt = 0; nt < 4; ++nt)
                Y[(size_t)row * 64 + nt * 16 + lr] =
                    (ushort_t)f2bf(acc[nt][m] * s);
        }
    }
}

// ---- gather SPMM 1 (bf16 payload): h = relu(sum*isq_in + b1)*isq_out ----
__global__ __launch_bounds__(256) void k_gather_h(
    const int* __restrict__ row_ptr, const int* __restrict__ edge_src,
    const ushort_t* __restrict__ x, const float* __restrict__ isq_in,
    const float* __restrict__ isq_out, const float* __restrict__ b1,
    float* __restrict__ h, int n)
{
    int col  = threadIdx.x & 63;
    int node = __builtin_amdgcn_readfirstlane(blockIdx.x * 4 + (threadIdx.x >> 6));
    if (node >= n) return;
    // hoisted epilogue operands (overlap gather latency)
    float si = isq_in[node];
    float so = isq_out[node];
    float bb = b1[col];
    int j = row_ptr[node], jend = row_ptr[node + 1];
    float a0 = 0.f, a1 = 0.f, a2 = 0.f, a3 = 0.f;
    float a4 = 0.f, a5 = 0.f, a6 = 0.f, a7 = 0.f;
    for (; j + 7 < jend; j += 8) {
        int e0 = edge_src[j],     e1 = edge_src[j + 1];
        int e2 = edge_src[j + 2], e3 = edge_src[j + 3];
        int e4 = edge_src[j + 4], e5 = edge_src[j + 5];
        int e6 = edge_src[j + 6], e7 = edge_src[j + 7];
        a0 += bf2f(x[(size_t)e0 * 64 + col]);
        a1 += bf2f(x[(size_t)e1 * 64 + col]);
        a2 += bf2f(x[(size_t)e2 * 64 + col]);
        a3 += bf2f(x[(size_t)e3 * 64 + col]);
        a4 += bf2f(x[(size_t)e4 * 64 + col]);
        a5 += bf2f(x[(size_t)e5 * 64 + col]);
        a6 += bf2f(x[(size_t)e6 * 64 + col]);
        a7 += bf2f(x[(size_t)e7 * 64 + col]);
    }
    for (; j + 1 < jend; j += 2) {
        int e0 = edge_src[j], e1 = edge_src[j + 1];
        a0 += bf2f(x[(size_t)e0 * 64 + col]);
        a1 += bf2f(x[(size_t)e1 * 64 + col]);
    }
    if (j < jend) a2 += bf2f(x[(size_t)edge_src[j] * 64 + col]);
    float acc = ((a0 + a1) + (a2 + a3)) + ((a4 + a5) + (a6 + a7));
    h[(size_t)node * 64 + col] = fmaxf(acc * si + bb, 0.f) * so;
}

// ---- GEMM23 f32 (K=64): t23 (bf16) = h @ wc ----
__global__ __launch_bounds__(256) void k_gemm2(
    const float* __restrict__ X, const float* __restrict__ W,
    ushort_t* __restrict__ Y, int n)
{
    __shared__ float sx[64][68];
    __shared__ float sw[64][64];
    const int tid  = threadIdx.x;
    const int colp = tid & 31;
    const int rg   = tid >> 5;
    const int row0 = blockIdx.x * 64;

    float2 acc[8];
#pragma unroll
    for (int i = 0; i < 8; ++i) acc[i] = make_float2(0.f, 0.f);

#pragma unroll
    for (int p = 0; p < 4; ++p) {
        int u = p * 256 + tid;
        int r = u >> 4, c4 = (u & 15) * 4;
        int row = row0 + r;
        float4 v = make_float4(0.f, 0.f, 0.f, 0.f);
        if (row < n) v = *(const float4*)&X[(size_t)row * 64 + c4];
        *(float4*)&sx[r][c4] = v;
        *(float4*)&sw[r][c4] = *(const float4*)&W[u * 4];
    }
    __syncthreads();

#pragma unroll 4
    for (int k4 = 0; k4 < 64; k4 += 4) {
        float2 w0 = *(const float2*)&sw[k4 + 0][colp * 2];
        float2 w1 = *(const float2*)&sw[k4 + 1][colp * 2];
        float2 w2 = *(const float2*)&sw[k4 + 2][colp * 2];
        float2 w3 = *(const float2*)&sw[k4 + 3][colp * 2];
#pragma unroll
        for (int i = 0; i < 8; ++i) {
            float4 f = *(const float4*)&sx[rg * 8 + i][k4];
            acc[i].x += f.x * w0.x + f.y * w1.x + f.z * w2.x + f.w * w3.x;
            acc[i].y += f.x * w0.y + f.y * w1.y + f.z * w2.y + f.w * w3.y;
        }
    }

#pragma unroll
    for (int i = 0; i < 8; ++i) {
        int row = row0 + rg * 8 + i;
        if (row < n) {
            unsigned lo = (unsigned)(unsigned short)f2bf(acc[i].x);
            unsigned hi = (unsigned)(unsigned short)f2bf(acc[i].y);
            ((unsigned*)Y)[(size_t)row * 32 + colp] = (hi << 16) | lo;
        }
    }
}

// ---- gather SPMM 2 (bf16 payload) + final: out = [z | mean | log_std] ----
__global__ __launch_bounds__(256) void k_gather_final(
    const int* __restrict__ row_ptr, const int* __restrict__ edge_src,
    const ushort_t* __restrict__ t23, const float* __restrict__ isq_in,
    const float* __restrict__ b2, const float* __restrict__ b3,
    const float* __restrict__ noise, float* __restrict__ out, int n)
{
    int lane = threadIdx.x & 63;
    int node = __builtin_amdgcn_readfirstlane(blockIdx.x * 4 + (threadIdx.x >> 6));
    if (node >= n) return;
    // hoisted epilogue operands
    float si   = isq_in[node];
    float bias = (lane < 32) ? b2[lane] : b3[lane - 32];
    int total  = n * 32;
    int base   = node * 32 + (lane & 31);
    float nz   = (lane < 32) ? noise[base] : 0.f;
    int j = row_ptr[node], jend = row_ptr[node + 1];
    float a0 = 0.f, a1 = 0.f, a2 = 0.f, a3 = 0.f;
    float a4 = 0.f, a5 = 0.f, a6 = 0.f, a7 = 0.f;
    for (; j + 7 < jend; j += 8) {
        int e0 = edge_src[j],     e1 = edge_src[j + 1];
        int e2 = edge_src[j + 2], e3 = edge_src[j + 3];
        int e4 = edge_src[j + 4], e5 = edge_src[j + 5];
        int e6 = edge_src[j + 6], e7 = edge_src[j + 7];
        a0 += bf2f(t23[(size_t)e0 * 64 + lane]);
        a1 += bf2f(t23[(size_t)e1 * 64 + lane]);
        a2 += bf2f(t23[(size_t)e2 * 64 + lane]);
        a3 += bf2f(t23[(size_t)e3 * 64 + lane]);
        a4 += bf2f(t23[(size_t)e4 * 64 + lane]);
        a5 += bf2f(t23[(size_t)e5 * 64 + lane]);
        a6 += bf2f(t23[(size_t)e6 * 64 + lane]);
        a7 += bf2f(t23[(size_t)e7 * 64 + lane]);
    }
    for (; j + 1 < jend; j += 2) {
        int e0 = edge_src[j], e1 = edge_src[j + 1];
        a0 += bf2f(t23[(size_t)e0 * 64 + lane]);
        a1 += bf2f(t23[(size_t)e1 * 64 + lane]);
    }
    if (j < jend) a2 += bf2f(t23[(size_t)edge_src[j] * 64 + lane]);
    float acc = ((a0 + a1) + (a2 + a3)) + ((a4 + a5) + (a6 + a7));
    float v  = acc * si + bias;
    float lv = __shfl(v, lane | 32, 64);
    if (lane < 32) {
        float z = v + nz * expf(lv);
        out[base]         = z;
        out[total + base] = v;
    } else {
        out[2 * total + base] = v;
    }
}

extern "C" void kernel_launch(void* const* d_in, const int* in_sizes, int n_in,
                              void* d_out, int out_size, void* d_ws, size_t ws_size,
                              hipStream_t stream)
{
    const float* feat  = (const float*)d_in[0];
    const int*   src   = (const int*)d_in[1];
    const int*   dst   = (const int*)d_in[2];
    const float* noise = (const float*)d_in[3];
    const float* W1    = (const float*)d_in[4];
    const float* b1    = (const float*)d_in[5];
    const float* W2    = (const float*)d_in[6];
    const float* b2    = (const float*)d_in[7];
    const float* W3    = (const float*)d_in[8];
    const float* b3    = (const float*)d_in[9];

    const int n = in_sizes[0] / 512;
    const int e = in_sizes[1];

    float* ws      = (float*)d_ws;
    float* isq_out = ws;
    float* isq_in  = ws + n;
    float* bufA    = ws + 2 * (size_t)n;               // h_pre/t23 (bf16)
    float* bufB    = bufA + 64 * (size_t)n;            // h (f32)
    float* wc      = bufB + 64 * (size_t)n;            // 4096 f32
    short* w1f     = (short*)(wc + 64 * 64);           // 32768 shorts
    int*   ip      = (int*)(w1f + 512 * 64);
    int* row_ptr   = ip;
    int* cursor    = ip + (n + 1);
    int* partials  = cursor + n;
    int* edge_src  = partials + 512;
    int* degS = (int*)bufA;                            // transient overlay
    int* degD = degS + n;
    float* out = (float*)d_out;

    const int nb = (n + 255) / 256;
    const int z4 = (2 * n) / 4;

    k_setup<<<(z4 + 255) / 256, 256, 0, stream>>>(
        W1, W2, W3, w1f, wc, (int4*)degS, z4);

    k_deg_int<<<(e + 255) / 256, 256, 0, stream>>>(src, dst, degS, degD, e);

    k_scan_block_sums<<<nb, 256, 0, stream>>>(degD, partials, n);
    k_scan_partials<<<1, 512, 0, stream>>>(partials, nb);
    k_scan_final<<<nb, 256, 0, stream>>>(
        degD, degS, partials, row_ptr, cursor, isq_out, isq_in, n);
    k_scatter<<<(e + 255) / 256, 256, 0, stream>>>(src, dst, cursor, edge_src, e);

    k_gemm1_mfma<<<(n + 63) / 64, 256, 0, stream>>>(
        feat, w1f, isq_out, (ushort_t*)bufA, n);

    k_gather_h<<<(n + 3) / 4, 256, 0, stream>>>(
        row_ptr, edge_src, (const ushort_t*)bufA, isq_in, isq_out, b1, bufB, n);

    k_gemm2<<<(n + 63) / 64, 256, 0, stream>>>(bufB, wc, (ushort_t*)bufA, n);

    k_gather_final<<<(n + 3) / 4, 256, 0, stream>>>(
        row_ptr, edge_src, (const ushort_t*)bufA, isq_in, b2, b3, noise, out, n);
}

// Round 9
// 259.255 us; speedup vs baseline: 1.1809x; 1.0277x over previous
//
#include <hip/hip_runtime.h>
#include <hip/hip_bf16.h>

// ---------------------------------------------------------------------------
// VGAE forward, round 9: round-8 fusion with the race fixed.
//  - k_gather_gemm2 reads h_pre from bufA, writes t23 to bufB (DISTINCT
//    buffer; r8 wrote t23 into bufA while other blocks still gathered from
//    it -> race, absmax 0.36).
//  - sched_barrier(0) after the LDS-handoff lgkmcnt(0) (rule #18).
//
// d_ws layout:
//   isq_out [n], isq_in [n]
//   bufA [64n f32 worth] : degS/degD overlay -> h_pre (bf16)
//   bufB [64n f32 worth] : t23 (bf16)
//   wc   [64*64 f32]     : [W2|W3] combined, natural [k][col]
//   w1f  [32768 shorts]  : W1 bf16 MFMA-fragment-linear
//   ints: row_ptr[n+1], cursor[n], partials[512], edge_src[e]
// ---------------------------------------------------------------------------

typedef __attribute__((ext_vector_type(8))) short short8;
typedef __attribute__((ext_vector_type(4))) float f32x4;
typedef unsigned short ushort_t;

static __device__ inline short f2bf(float f)
{
    union { __hip_bfloat16 h; short s; } u;
    u.h = __float2bfloat16(f);
    return u.s;
}

static __device__ inline float bf2f(ushort_t u)
{
    union { float f; unsigned v; } w;
    w.v = ((unsigned)u) << 16;
    return w.f;
}

static __device__ inline short8 cvt8(float4 lo, float4 hi)
{
    short8 r;
    r[0] = f2bf(lo.x); r[1] = f2bf(lo.y); r[2] = f2bf(lo.z); r[3] = f2bf(lo.w);
    r[4] = f2bf(hi.x); r[5] = f2bf(hi.y); r[6] = f2bf(hi.z); r[7] = f2bf(hi.w);
    return r;
}

// ---- merged setup: zero degree hist, build wc, pack w1 ----
__global__ __launch_bounds__(256) void k_setup(
    const float* __restrict__ W1, const float* __restrict__ W2,
    const float* __restrict__ W3, short* __restrict__ w1f,
    float* __restrict__ wc, int4* __restrict__ zp, int z4)
{
    int gid = blockIdx.x * 256 + threadIdx.x;
    if (gid < z4) zp[gid] = make_int4(0, 0, 0, 0);
    if (gid < 64 * 64) {
        int k = gid >> 6, c = gid & 63;
        wc[gid] = (c < 32) ? W2[k * 32 + c] : W3[k * 32 + (c - 32)];
    }
    if (gid < 512 * 64) {
        int k = gid >> 6, c = gid & 63;
        int kt = k >> 5, kk = k & 31, nt = c >> 4, lr = c & 15;
        int kg = kk >> 3, j = kk & 7;
        int l = kg * 16 + lr;
        w1f[(kt * 4 + nt) * 512 + l * 8 + j] = f2bf(W1[gid]);
    }
}

__global__ __launch_bounds__(256) void k_deg_int(
    const int* __restrict__ src, const int* __restrict__ dst,
    int* __restrict__ degS, int* __restrict__ degD, int e)
{
    int gid = blockIdx.x * 256 + threadIdx.x;
    if (gid >= e) return;
    atomicAdd(&degS[src[gid]], 1);
    atomicAdd(&degD[dst[gid]], 1);
}

__global__ __launch_bounds__(256) void k_scan_block_sums(
    const int* __restrict__ deg, int* __restrict__ partials, int n)
{
    __shared__ int red[256];
    int gid = blockIdx.x * 256 + threadIdx.x;
    red[threadIdx.x] = (gid < n) ? deg[gid] : 0;
    __syncthreads();
    for (int s = 128; s > 0; s >>= 1) {
        if (threadIdx.x < s) red[threadIdx.x] += red[threadIdx.x + s];
        __syncthreads();
    }
    if (threadIdx.x == 0) partials[blockIdx.x] = red[0];
}

__global__ __launch_bounds__(512) void k_scan_partials(
    int* __restrict__ partials, int nb)
{
    __shared__ int s[512];
    int t = threadIdx.x;
    s[t] = (t < nb) ? partials[t] : 0;
    __syncthreads();
    for (int d = 1; d < 512; d <<= 1) {
        int v = (t >= d) ? s[t - d] : 0;
        __syncthreads();
        s[t] += v;
        __syncthreads();
    }
    if (t < nb) partials[t] = (t == 0) ? 0 : s[t - 1];
}

__global__ __launch_bounds__(256) void k_scan_final(
    const int* __restrict__ degD, const int* __restrict__ degS,
    const int* __restrict__ partials,
    int* __restrict__ row_ptr, int* __restrict__ cursor,
    float* __restrict__ isq_out, float* __restrict__ isq_in, int n)
{
    __shared__ int s[256];
    int t = threadIdx.x;
    int gid = blockIdx.x * 256 + t;
    int v = (gid < n) ? degD[gid] : 0;
    s[t] = v;
    __syncthreads();
    for (int d = 1; d < 256; d <<= 1) {
        int u = (t >= d) ? s[t - d] : 0;
        __syncthreads();
        s[t] += u;
        __syncthreads();
    }
    int start = partials[blockIdx.x] + s[t] - v;
    if (gid < n) {
        row_ptr[gid] = start;
        cursor[gid]  = start;
        isq_in[gid]  = 1.0f / sqrtf((float)max(v, 1));
        isq_out[gid] = 1.0f / sqrtf((float)max(degS[gid], 1));
    }
    if (gid == n - 1) row_ptr[n] = start + v;
}

__global__ __launch_bounds__(256) void k_scatter(
    const int* __restrict__ src, const int* __restrict__ dst,
    int* __restrict__ cursor, int* __restrict__ edge_src, int e)
{
    int gid = blockIdx.x * 256 + threadIdx.x;
    if (gid >= e) return;
    int pos = atomicAdd(&cursor[dst[gid]], 1);
    edge_src[pos] = src[gid];
}

// ---- GEMM1 bf16 MFMA: h_pre[n][64] (bf16) = (X @ W1) * scale[row] ----
// 16 rows/wave; A prefetch depth 4 (kt&3), B depth 2 (kt&1), all static.
__global__ __launch_bounds__(256) void k_gemm1_mfma(
    const float* __restrict__ X, const short* __restrict__ w1f,
    const float* __restrict__ scale, ushort_t* __restrict__ Y, int n)
{
    const int tid  = threadIdx.x;
    const int l    = tid & 63;
    const int wv   = tid >> 6;
    const int row0 = (blockIdx.x * 4 + wv) * 16;
    const int lr   = l & 15;
    const int kg   = l >> 4;

    int ra = row0 + lr;  if (ra >= n) ra = n - 1;
    const float* pa = X + (size_t)ra * 512 + kg * 8;
    const short* pb = w1f + l * 8;

    f32x4 acc[4];
#pragma unroll
    for (int j = 0; j < 4; ++j) acc[j] = (f32x4){0.f, 0.f, 0.f, 0.f};

    float4 alo[4], ahi[4];
#pragma unroll
    for (int s = 0; s < 4; ++s) {
        alo[s] = *(const float4*)(pa + s * 32);
        ahi[s] = *(const float4*)(pa + s * 32 + 4);
    }
    short8 bst[2][4];
#pragma unroll
    for (int s = 0; s < 2; ++s) {
        const short* q = pb + (size_t)s * 2048;
        bst[s][0] = *(const short8*)(q);
        bst[s][1] = *(const short8*)(q + 512);
        bst[s][2] = *(const short8*)(q + 1024);
        bst[s][3] = *(const short8*)(q + 1536);
    }

#pragma unroll
    for (int kt = 0; kt < 16; ++kt) {
        short8 ca = cvt8(alo[kt & 3], ahi[kt & 3]);
        if (kt + 4 < 16) {                   // refill A stage just consumed
            const float* q = pa + (kt + 4) * 32;
            alo[kt & 3] = *(const float4*)(q);
            ahi[kt & 3] = *(const float4*)(q + 4);
        }
        short8 cb0 = bst[kt & 1][0], cb1 = bst[kt & 1][1];
        short8 cb2 = bst[kt & 1][2], cb3 = bst[kt & 1][3];
        if (kt + 2 < 16) {                   // refill B stage just consumed
            const short* q = pb + (size_t)(kt + 2) * 2048;
            bst[kt & 1][0] = *(const short8*)(q);
            bst[kt & 1][1] = *(const short8*)(q + 512);
            bst[kt & 1][2] = *(const short8*)(q + 1024);
            bst[kt & 1][3] = *(const short8*)(q + 1536);
        }
        acc[0] = __builtin_amdgcn_mfma_f32_16x16x32_bf16(ca, cb0, acc[0], 0, 0, 0);
        acc[1] = __builtin_amdgcn_mfma_f32_16x16x32_bf16(ca, cb1, acc[1], 0, 0, 0);
        acc[2] = __builtin_amdgcn_mfma_f32_16x16x32_bf16(ca, cb2, acc[2], 0, 0, 0);
        acc[3] = __builtin_amdgcn_mfma_f32_16x16x32_bf16(ca, cb3, acc[3], 0, 0, 0);
    }

#pragma unroll
    for (int m = 0; m < 4; ++m) {
        int row = row0 + kg * 4 + m;
        if (row < n) {
            float s = scale[row];
#pragma unroll
            for (int nt = 0; nt < 4; ++nt)
                Y[(size_t)row * 64 + nt * 16 + lr] =
                    (ushort_t)f2bf(acc[nt][m] * s);
        }
    }
}

// ---- FUSED gather1 + gemm2: t23 = (relu(gather*isq_in+b1)*isq_out) @ wc ----
// Reads h_pre (bufA), writes t23 (bufB) -- distinct buffers, no race.
__global__ __launch_bounds__(256) void k_gather_gemm2(
    const int* __restrict__ row_ptr, const int* __restrict__ edge_src,
    const ushort_t* __restrict__ x, const float* __restrict__ isq_in,
    const float* __restrict__ isq_out, const float* __restrict__ b1,
    const float* __restrict__ wc, ushort_t* __restrict__ t23, int n)
{
    __shared__ float swc[64 * 64];   // 16 KB, [k][col]
    __shared__ float sh[4][64];      // wave-private h rows
    const int tid = threadIdx.x;
    const int col = tid & 63;
    const int wv  = tid >> 6;

    // stage wc cooperatively (16 f32 per thread)
#pragma unroll
    for (int p = 0; p < 4; ++p) {
        int u = p * 256 + tid;
        *(float4*)&swc[u * 4] = *(const float4*)&wc[u * 4];
    }
    __syncthreads();

    const float bb = b1[col];

#pragma unroll 1
    for (int i = 0; i < 4; ++i) {
        int node = blockIdx.x * 16 + wv * 4 + i;
        if (node >= n) break;
        float si = isq_in[node];
        float so = isq_out[node];
        int j = row_ptr[node], jend = row_ptr[node + 1];
        float a0 = 0.f, a1 = 0.f, a2 = 0.f, a3 = 0.f;
        float a4 = 0.f, a5 = 0.f, a6 = 0.f, a7 = 0.f;
        for (; j + 7 < jend; j += 8) {
            int e0 = edge_src[j],     e1 = edge_src[j + 1];
            int e2 = edge_src[j + 2], e3 = edge_src[j + 3];
            int e4 = edge_src[j + 4], e5 = edge_src[j + 5];
            int e6 = edge_src[j + 6], e7 = edge_src[j + 7];
            a0 += bf2f(x[(size_t)e0 * 64 + col]);
            a1 += bf2f(x[(size_t)e1 * 64 + col]);
            a2 += bf2f(x[(size_t)e2 * 64 + col]);
            a3 += bf2f(x[(size_t)e3 * 64 + col]);
            a4 += bf2f(x[(size_t)e4 * 64 + col]);
            a5 += bf2f(x[(size_t)e5 * 64 + col]);
            a6 += bf2f(x[(size_t)e6 * 64 + col]);
            a7 += bf2f(x[(size_t)e7 * 64 + col]);
        }
        for (; j + 1 < jend; j += 2) {
            int e0 = edge_src[j], e1 = edge_src[j + 1];
            a0 += bf2f(x[(size_t)e0 * 64 + col]);
            a1 += bf2f(x[(size_t)e1 * 64 + col]);
        }
        if (j < jend) a2 += bf2f(x[(size_t)edge_src[j] * 64 + col]);
        float acc = ((a0 + a1) + (a2 + a3)) + ((a4 + a5) + (a6 + a7));
        float hval = fmaxf(acc * si + bb, 0.f) * so;

        // wave-private cross-lane handoff: LDS write -> waitcnt -> reads.
        sh[wv][col] = hval;
        asm volatile("s_waitcnt lgkmcnt(0)" ::: "memory");
        __builtin_amdgcn_sched_barrier(0);

        float t = 0.f;
#pragma unroll
        for (int k4 = 0; k4 < 64; k4 += 4) {
            float4 hb = *(const float4*)&sh[wv][k4];
            t += hb.x * swc[(k4 + 0) * 64 + col]
               + hb.y * swc[(k4 + 1) * 64 + col]
               + hb.z * swc[(k4 + 2) * 64 + col]
               + hb.w * swc[(k4 + 3) * 64 + col];
        }
        t23[(size_t)node * 64 + col] = (ushort_t)f2bf(t);
    }
}

// ---- gather SPMM 2 (bf16 payload) + final: out = [z | mean | log_std] ----
__global__ __launch_bounds__(256) void k_gather_final(
    const int* __restrict__ row_ptr, const int* __restrict__ edge_src,
    const ushort_t* __restrict__ t23, const float* __restrict__ isq_in,
    const float* __restrict__ b2, const float* __restrict__ b3,
    const float* __restrict__ noise, float* __restrict__ out, int n)
{
    int lane = threadIdx.x & 63;
    int node = __builtin_amdgcn_readfirstlane(blockIdx.x * 4 + (threadIdx.x >> 6));
    if (node >= n) return;
    float si   = isq_in[node];
    float bias = (lane < 32) ? b2[lane] : b3[lane - 32];
    int total  = n * 32;
    int base   = node * 32 + (lane & 31);
    float nz   = (lane < 32) ? noise[base] : 0.f;
    int j = row_ptr[node], jend = row_ptr[node + 1];
    float a0 = 0.f, a1 = 0.f, a2 = 0.f, a3 = 0.f;
    float a4 = 0.f, a5 = 0.f, a6 = 0.f, a7 = 0.f;
    for (; j + 7 < jend; j += 8) {
        int e0 = edge_src[j],     e1 = edge_src[j + 1];
        int e2 = edge_src[j + 2], e3 = edge_src[j + 3];
        int e4 = edge_src[j + 4], e5 = edge_src[j + 5];
        int e6 = edge_src[j + 6], e7 = edge_src[j + 7];
        a0 += bf2f(t23[(size_t)e0 * 64 + lane]);
        a1 += bf2f(t23[(size_t)e1 * 64 + lane]);
        a2 += bf2f(t23[(size_t)e2 * 64 + lane]);
        a3 += bf2f(t23[(size_t)e3 * 64 + lane]);
        a4 += bf2f(t23[(size_t)e4 * 64 + lane]);
        a5 += bf2f(t23[(size_t)e5 * 64 + lane]);
        a6 += bf2f(t23[(size_t)e6 * 64 + lane]);
        a7 += bf2f(t23[(size_t)e7 * 64 + lane]);
    }
    for (; j + 1 < jend; j += 2) {
        int e0 = edge_src[j], e1 = edge_src[j + 1];
        a0 += bf2f(t23[(size_t)e0 * 64 + lane]);
        a1 += bf2f(t23[(size_t)e1 * 64 + lane]);
    }
    if (j < jend) a2 += bf2f(t23[(size_t)edge_src[j] * 64 + lane]);
    float acc = ((a0 + a1) + (a2 + a3)) + ((a4 + a5) + (a6 + a7));
    float v  = acc * si + bias;
    float lv = __shfl(v, lane | 32, 64);
    if (lane < 32) {
        float z = v + nz * expf(lv);
        out[base]         = z;
        out[total + base] = v;
    } else {
        out[2 * total + base] = v;
    }
}

extern "C" void kernel_launch(void* const* d_in, const int* in_sizes, int n_in,
                              void* d_out, int out_size, void* d_ws, size_t ws_size,
                              hipStream_t stream)
{
    const float* feat  = (const float*)d_in[0];
    const int*   src   = (const int*)d_in[1];
    const int*   dst   = (const int*)d_in[2];
    const float* noise = (const float*)d_in[3];
    const float* W1    = (const float*)d_in[4];
    const float* b1    = (const float*)d_in[5];
    const float* W2    = (const float*)d_in[6];
    const float* b2    = (const float*)d_in[7];
    const float* W3    = (const float*)d_in[8];
    const float* b3    = (const float*)d_in[9];

    const int n = in_sizes[0] / 512;
    const int e = in_sizes[1];

    float* ws      = (float*)d_ws;
    float* isq_out = ws;
    float* isq_in  = ws + n;
    float* bufA    = ws + 2 * (size_t)n;               // h_pre (bf16)
    float* bufB    = bufA + 64 * (size_t)n;            // t23 (bf16)
    float* wc      = bufB + 64 * (size_t)n;            // 4096 f32
    short* w1f     = (short*)(wc + 64 * 64);           // 32768 shorts
    int*   ip      = (int*)(w1f + 512 * 64);
    int* row_ptr   = ip;
    int* cursor    = ip + (n + 1);
    int* partials  = cursor + n;
    int* edge_src  = partials + 512;
    int* degS = (int*)bufA;                            // transient overlay
    int* degD = degS + n;
    float* out = (float*)d_out;

    const int nb = (n + 255) / 256;
    const int z4 = (2 * n) / 4;

    k_setup<<<(z4 + 255) / 256, 256, 0, stream>>>(
        W1, W2, W3, w1f, wc, (int4*)degS, z4);

    k_deg_int<<<(e + 255) / 256, 256, 0, stream>>>(src, dst, degS, degD, e);

    k_scan_block_sums<<<nb, 256, 0, stream>>>(degD, partials, n);
    k_scan_partials<<<1, 512, 0, stream>>>(partials, nb);
    k_scan_final<<<nb, 256, 0, stream>>>(
        degD, degS, partials, row_ptr, cursor, isq_out, isq_in, n);
    k_scatter<<<(e + 255) / 256, 256, 0, stream>>>(src, dst, cursor, edge_src, e);

    k_gemm1_mfma<<<(n + 63) / 64, 256, 0, stream>>>(
        feat, w1f, isq_out, (ushort_t*)bufA, n);

    k_gather_gemm2<<<(n + 15) / 16, 256, 0, stream>>>(
        row_ptr, edge_src, (const ushort_t*)bufA, isq_in, isq_out, b1,
        wc, (ushort_t*)bufB, n);

    k_gather_final<<<(n + 3) / 4, 256, 0, stream>>>(
        row_ptr, edge_src, (const ushort_t*)bufB, isq_in, b2, b3, noise, out, n);
}